// Round 2
// baseline (3136.572 us; speedup 1.0000x reference)
//
#include <hip/hip_runtime.h>
#include <cstdint>
#include <cstddef>

#define T_DIM 128
#define B_DIM 256
#define F_DIM 512
#define H_DIM 1024
#define G_DIM 4096   // 4*H
#define M_DIM (T_DIM * B_DIM)  // 32768

typedef unsigned short u16;
typedef unsigned short u16x8 __attribute__((ext_vector_type(8)));
typedef unsigned short u16x4 __attribute__((ext_vector_type(4)));
typedef __bf16 bf16x8 __attribute__((ext_vector_type(8)));
typedef float f32x4 __attribute__((ext_vector_type(4)));

__device__ __forceinline__ float bf2f(u16 u) {
    union { unsigned v; float f; } x; x.v = ((unsigned)u) << 16; return x.f;
}
__device__ __forceinline__ u16 f2bf(float f) {
    union { float f; unsigned v; } x; x.f = f;
    return (u16)((x.v + 0x7fffu + ((x.v >> 16) & 1u)) >> 16);
}

__device__ __forceinline__ f32x4 mfma16(u16x8 a, u16x8 b, f32x4 c) {
    return __builtin_amdgcn_mfma_f32_16x16x32_bf16(
        __builtin_bit_cast(bf16x8, a), __builtin_bit_cast(bf16x8, b), c, 0, 0, 0);
}

__device__ __forceinline__ void gl_lds16(const void* g, void* s) {
    __builtin_amdgcn_global_load_lds(
        (const __attribute__((address_space(1))) void*)g,
        (__attribute__((address_space(3))) void*)s, 16, 0, 0);
}

__device__ __forceinline__ float sigm(float x) { return 1.0f / (1.0f + __expf(-x)); }
__device__ __forceinline__ float tanh_fast(float x) {
    float e = __expf(2.0f * x);
    return 1.0f - 2.0f / (e + 1.0f);
}

// C[M,N] = epi(A[M,K] * B[N,K]^T + bias), bf16 in/out, f32 accum.
// 128x128 tile, BK=64, 4 waves (2x2), each wave 64x64 = 4x4 frags of 16x16x32.
template <int EPI>
__global__ __launch_bounds__(256) void gemm_bt128(
    const u16* __restrict__ A, const u16* __restrict__ B,
    const float* __restrict__ bias, u16* __restrict__ C, int K, int N) {
    __shared__ u16 lA[128 * 64];
    __shared__ u16 lB[128 * 64];
    const int lane = threadIdx.x & 63;
    const int wave = threadIdx.x >> 6;
    const int wr = wave >> 1, wc = wave & 1;
    const int bm = blockIdx.x, bn = blockIdx.y;
    f32x4 acc[4][4] = {};
    const int srow = lane >> 3;
    const int scol = (lane & 7) * 8;
    const u16* Abase = A + (size_t)(bm * 128 + srow) * K + scol;
    const u16* Bbase = B + (size_t)(bn * 128 + srow) * K + scol;

    for (int k0 = 0; k0 < K; k0 += 64) {
#pragma unroll
        for (int j = 0; j < 4; ++j) {
            int chunk = wave * 4 + j;
            gl_lds16(Abase + (size_t)(chunk * 8) * K + k0, lA + chunk * 512);
            gl_lds16(Bbase + (size_t)(chunk * 8) * K + k0, lB + chunk * 512);
        }
        __syncthreads();
        const u16* pA = lA + (wr * 64 + (lane & 15)) * 64 + (lane >> 4) * 8;
        const u16* pB = lB + (wc * 64 + (lane & 15)) * 64 + (lane >> 4) * 8;
#pragma unroll
        for (int kk = 0; kk < 2; ++kk) {
            u16x8 a[4], b[4];
#pragma unroll
            for (int m = 0; m < 4; ++m) a[m] = *(const u16x8*)(pA + m * 1024 + kk * 32);
#pragma unroll
            for (int n = 0; n < 4; ++n) b[n] = *(const u16x8*)(pB + n * 1024 + kk * 32);
#pragma unroll
            for (int m = 0; m < 4; ++m)
#pragma unroll
                for (int n = 0; n < 4; ++n)
                    acc[m][n] = mfma16(a[m], b[n], acc[m][n]);
        }
        __syncthreads();
    }
    // epilogue: C/D layout col=lane&15, row=(lane>>4)*4+i  [m89-verified]
#pragma unroll
    for (int n = 0; n < 4; ++n) {
        int col = bn * 128 + wc * 64 + n * 16 + (lane & 15);
        float bv = bias[col];
#pragma unroll
        for (int m = 0; m < 4; ++m) {
            size_t row = (size_t)bm * 128 + wr * 64 + m * 16 + ((lane >> 4) * 4);
#pragma unroll
            for (int i = 0; i < 4; ++i) {
                float v = acc[m][n][i] + bv;
                if (EPI == 1) v = (v >= 0.0f) ? v : 0.01f * v;
                C[(row + i) * (size_t)N + col] = f2bf(v);
            }
        }
    }
}

// One LSTM time step, fused: gates GEMM (h_prev @ Whh_p^T) + xg + mask + activations
// + c/h update + value-head partial dot. Tile 64x64 over [B=256, G=4096], grid (4,64).
__global__ __launch_bounds__(256) void lstm_step(
    const u16* __restrict__ hprev, const u16* __restrict__ Whh,
    const u16* __restrict__ xg, const int* __restrict__ dones,
    const float* __restrict__ Wv, float* __restrict__ cbuf,
    float* __restrict__ hbuf, u16* __restrict__ hnext,
    float* __restrict__ value, int store_h) {
    __shared__ u16 lA[64 * 64];
    __shared__ u16 lB[64 * 64];
    __shared__ float lepi[64 * 64];
    const int lane = threadIdx.x & 63;
    const int wave = threadIdx.x >> 6;
    const int wr = wave >> 1, wc = wave & 1;
    const int bm = blockIdx.x, bn = blockIdx.y;
    f32x4 acc[2][2] = {};
    const int srow = lane >> 3;
    const int scol = (lane & 7) * 8;
    const u16* Abase = hprev + (size_t)(bm * 64 + srow) * H_DIM + scol;
    const u16* Bbase = Whh + (size_t)(bn * 64 + srow) * H_DIM + scol;

    for (int k0 = 0; k0 < H_DIM; k0 += 64) {
#pragma unroll
        for (int j = 0; j < 2; ++j) {
            int chunk = wave * 2 + j;
            gl_lds16(Abase + (size_t)(chunk * 8) * H_DIM + k0, lA + chunk * 512);
            gl_lds16(Bbase + (size_t)(chunk * 8) * H_DIM + k0, lB + chunk * 512);
        }
        __syncthreads();
        const u16* pA = lA + (wr * 32 + (lane & 15)) * 64 + (lane >> 4) * 8;
        const u16* pB = lB + (wc * 32 + (lane & 15)) * 64 + (lane >> 4) * 8;
#pragma unroll
        for (int kk = 0; kk < 2; ++kk) {
            u16x8 a0 = *(const u16x8*)(pA + kk * 32);
            u16x8 a1 = *(const u16x8*)(pA + 1024 + kk * 32);
            u16x8 b0 = *(const u16x8*)(pB + kk * 32);
            u16x8 b1 = *(const u16x8*)(pB + 1024 + kk * 32);
            acc[0][0] = mfma16(a0, b0, acc[0][0]);
            acc[0][1] = mfma16(a0, b1, acc[0][1]);
            acc[1][0] = mfma16(a1, b0, acc[1][0]);
            acc[1][1] = mfma16(a1, b1, acc[1][1]);
        }
        __syncthreads();
    }
    // scatter gate pre-activations (GEMM part) to LDS
#pragma unroll
    for (int m = 0; m < 2; ++m)
#pragma unroll
        for (int n = 0; n < 2; ++n)
#pragma unroll
            for (int i = 0; i < 4; ++i)
                lepi[(wr * 32 + m * 16 + (lane >> 4) * 4 + i) * 64 +
                     wc * 32 + n * 16 + (lane & 15)] = acc[m][n][i];
    __syncthreads();

    // per-thread: one batch row, 4 units (permuted layout: col = 4*unit + gate)
    const int r = threadIdx.x & 63;
    const int ublk = threadIdx.x >> 6;
    const int bg = bm * 64 + r;
    const float mb = (dones[bg] == 0) ? 1.0f : 0.0f;
    const int ucol = bn * 16 + ublk * 4;  // global unit index base
    float4 cv = *(const float4*)(cbuf + (size_t)bg * H_DIM + ucol);
    float cold[4] = {cv.x, cv.y, cv.z, cv.w};
    float co[4], ho[4];
    float vpart = 0.0f;
#pragma unroll
    for (int uu = 0; uu < 4; ++uu) {
        const int ut = ublk * 4 + uu;  // unit within tile (0..15)
        const float* gp = &lepi[r * 64 + ut * 4];
        u16x4 xv = *(const u16x4*)(xg + (size_t)bg * G_DIM + (size_t)bn * 64 + ut * 4);
        float gi = bf2f(xv[0]) + mb * gp[0];
        float gf = bf2f(xv[1]) + mb * gp[1];
        float gg = bf2f(xv[2]) + mb * gp[2];
        float go = bf2f(xv[3]) + mb * gp[3];
        float i_ = sigm(gi);
        float f_ = sigm(gf);
        float g_ = tanh_fast(gg);
        float o_ = sigm(go);
        float cn = f_ * (mb * cold[uu]) + i_ * g_;
        float hn = o_ * tanh_fast(cn);
        co[uu] = cn;
        ho[uu] = hn;
        float lr = (hn >= 0.0f) ? hn : 0.01f * hn;
        vpart += lr * Wv[ucol + uu];
    }
    *(float4*)(cbuf + (size_t)bg * H_DIM + ucol) = make_float4(co[0], co[1], co[2], co[3]);
    if (store_h)
        *(float4*)(hbuf + (size_t)bg * H_DIM + ucol) = make_float4(ho[0], ho[1], ho[2], ho[3]);
    u16x4 hb;
#pragma unroll
    for (int uu = 0; uu < 4; ++uu) hb[uu] = f2bf(ho[uu]);
    *(u16x4*)(hnext + (size_t)bg * H_DIM + ucol) = hb;
    atomicAdd(value + bg, vpart);
}

__global__ void k_cast_bf16(const float* __restrict__ in, u16* __restrict__ out, int n4) {
    int i = blockIdx.x * 256 + threadIdx.x;
    if (i < n4) {
        float4 v = *(const float4*)(in + (size_t)i * 4);
        u16x4 o;
        o[0] = f2bf(v.x); o[1] = f2bf(v.y); o[2] = f2bf(v.z); o[3] = f2bf(v.w);
        *(u16x4*)(out + (size_t)i * 4) = o;
    }
}

// out row (4n+q) = in row (q*H + n), cast to bf16. Grid: 4096 blocks x 256 threads.
__global__ void k_permute_w(const float* __restrict__ W, u16* __restrict__ Wp) {
    int row = blockIdx.x;
    int rin = (row & 3) * H_DIM + (row >> 2);
    int c = threadIdx.x * 4;
    float4 v = *(const float4*)(W + (size_t)rin * H_DIM + c);
    u16x4 o;
    o[0] = f2bf(v.x); o[1] = f2bf(v.y); o[2] = f2bf(v.z); o[3] = f2bf(v.w);
    *(u16x4*)(Wp + (size_t)row * H_DIM + c) = o;
}

__global__ void k_prep_bias(const float* __restrict__ b_ih, const float* __restrict__ b_hh,
                            float* __restrict__ bc) {
    int i = blockIdx.x * 256 + threadIdx.x;  // 0..4095
    int n = i >> 2, q = i & 3;
    bc[i] = b_ih[q * H_DIM + n] + b_hh[q * H_DIM + n];
}

__global__ void k_init(float* __restrict__ cbuf, u16* __restrict__ h0,
                       float* __restrict__ value, const float* __restrict__ bv) {
    int i = blockIdx.x * 256 + threadIdx.x;
    if (i < B_DIM * H_DIM) { cbuf[i] = 0.0f; h0[i] = 0; }
    if (i < T_DIM * B_DIM) value[i] = *bv;
}

extern "C" void kernel_launch(void* const* d_in, const int* in_sizes, int n_in,
                              void* d_out, int out_size, void* d_ws, size_t ws_size,
                              hipStream_t stream) {
    const float* x     = (const float*)d_in[0];
    const int*   dones = (const int*)d_in[1];
    const float* W1    = (const float*)d_in[2];
    const float* b1    = (const float*)d_in[3];
    const float* W_ih  = (const float*)d_in[4];
    const float* W_hh  = (const float*)d_in[5];
    const float* b_ih  = (const float*)d_in[6];
    const float* b_hh  = (const float*)d_in[7];
    const float* Wv    = (const float*)d_in[8];
    const float* bv    = (const float*)d_in[9];

    float* out   = (float*)d_out;
    float* value = out;                          // [T*B]
    float* hbuf  = out + (size_t)T_DIM * B_DIM;  // hidden[0] = h_T, [B*H]
    float* cbuf  = hbuf + (size_t)B_DIM * H_DIM; // hidden[1] = c_T, [B*H]

    // ---- workspace plan: adapt chunking to ws_size (R1 crash = ws overflow) ----
    const size_t MB = 1024 * 1024;
    int sh_t, xg_t;  // timesteps held by (x_bf,shr) and xg buffers
    if      (ws_size >= 400 * MB) { sh_t = T_DIM; xg_t = T_DIM; }
    else if (ws_size >= 160 * MB) { sh_t = T_DIM; xg_t = 16; }
    else if (ws_size >=  48 * MB) { sh_t = 8;     xg_t = 8; }
    else                          { sh_t = 4;     xg_t = 4; }

    char* ws = (char*)d_ws;
    size_t off = 0;
    auto alloc = [&](size_t bytes) {
        void* p = ws + off;
        off = (off + bytes + 255) & ~(size_t)255;
        return p;
    };
    u16*   x_bf  = (u16*)alloc((size_t)sh_t * B_DIM * F_DIM * 2);
    u16*   shr   = (u16*)alloc((size_t)sh_t * B_DIM * H_DIM * 2);
    u16*   xg    = (u16*)alloc((size_t)xg_t * B_DIM * G_DIM * 2);
    u16*   W1b   = (u16*)alloc((size_t)H_DIM * F_DIM * 2);
    u16*   Wihp  = (u16*)alloc((size_t)G_DIM * H_DIM * 2);
    u16*   Whhp  = (u16*)alloc((size_t)G_DIM * H_DIM * 2);
    float* bcomb = (float*)alloc((size_t)G_DIM * 4);
    u16*   hping = (u16*)alloc((size_t)B_DIM * H_DIM * 2);
    u16*   hpong = (u16*)alloc((size_t)B_DIM * H_DIM * 2);

    // ---- weight prep (once) ----
    k_cast_bf16<<<(H_DIM * F_DIM / 4) / 256, 256, 0, stream>>>(W1, W1b, H_DIM * F_DIM / 4);
    k_permute_w<<<G_DIM, 256, 0, stream>>>(W_ih, Wihp);
    k_permute_w<<<G_DIM, 256, 0, stream>>>(W_hh, Whhp);
    k_prep_bias<<<G_DIM / 256, 256, 0, stream>>>(b_ih, b_hh, bcomb);
    k_init<<<(B_DIM * H_DIM) / 256, 256, 0, stream>>>(cbuf, hping, value, bv);

    // phase-1 helper: shared[t0:t0+nt] = leaky_relu(x @ W1^T + b1) into shr (offset if full)
    auto phase1 = [&](int t0, int nt, u16* shr_dst) {
        int m = nt * B_DIM;
        int n4 = m * F_DIM / 4;
        k_cast_bf16<<<n4 / 256, 256, 0, stream>>>(x + (size_t)t0 * B_DIM * F_DIM, x_bf, n4);
        gemm_bt128<1><<<dim3(m / 128, H_DIM / 128), 256, 0, stream>>>(
            x_bf, W1b, b1, shr_dst, F_DIM, H_DIM);
    };

    if (sh_t == T_DIM) phase1(0, T_DIM, shr);

    for (int t0 = 0; t0 < T_DIM; t0 += xg_t) {
        const u16* shrA;
        if (sh_t == T_DIM) {
            shrA = shr + (size_t)t0 * B_DIM * H_DIM;
        } else {
            phase1(t0, xg_t, shr);
            shrA = shr;
        }
        // xg = shared @ W_ih_p^T + (b_ih+b_hh)_p, gate-permuted cols
        int m = xg_t * B_DIM;
        gemm_bt128<0><<<dim3(m / 128, G_DIM / 128), 256, 0, stream>>>(
            shrA, Wihp, bcomb, xg, H_DIM, G_DIM);

        for (int tt = 0; tt < xg_t; ++tt) {
            int t = t0 + tt;
            const u16* hp = (t & 1) ? hpong : hping;
            u16* hn = (t & 1) ? hping : hpong;
            lstm_step<<<dim3(B_DIM / 64, G_DIM / 64), 256, 0, stream>>>(
                hp, Whhp, xg + (size_t)tt * B_DIM * G_DIM, dones + (size_t)t * B_DIM,
                Wv, cbuf, hbuf, hn, value + (size_t)t * B_DIM, t == T_DIM - 1 ? 1 : 0);
        }
    }
}